// Round 10
// baseline (183.731 us; speedup 1.0000x reference)
//
#include <hip/hip_runtime.h>
#include <stdint.h>

#define NSITE 512
#define DD    64
#define NB    64
#define NO    10
#define NSEG  16
#define SEGLEN 32
#define SLAB_BYTES 32768   // fp32 site slab stride
#define PACK_BYTES 16384   // packed bf16 Wstk image (front half of slab)

typedef short bf16x8 __attribute__((ext_vector_type(8)));
typedef float f32x16 __attribute__((ext_vector_type(16)));

// trunc-pack two f32 -> packed bf16 dword (lo=a, hi=b) in ONE v_perm_b32
__device__ __forceinline__ uint32_t pk2(float a, float b) {
    return __builtin_amdgcn_perm(__float_as_uint(b), __float_as_uint(a), 0x07060302);
}

// packed f32 pair multiply / add: one VOP3P instruction each
__device__ __forceinline__ float2 pkmul2(float2 a, float2 b) {
    float2 r;
    asm("v_pk_mul_f32 %0, %1, %2" : "=v"(r) : "v"(a), "v"(b));
    return r;
}
__device__ __forceinline__ float2 pkadd2(float2 a, float2 b) {
    float2 r;
    asm("v_pk_add_f32 %0, %1, %2" : "=v"(r) : "v"(a), "v"(b));
    return r;
}

// ---------------------------------------------------------------------------
// Pack W fp32 [s][l][r][w] -> bf16 K-stacked A-operand image, IN PLACE (front
// 16 KB of each 32 KB slab).  Layout as before; stage1 A-frag read is
// *(uint4*)(ring + chunk*1024 + lane*16): lane-contiguous, conflict-free.
// ---------------------------------------------------------------------------
__global__ __launch_bounds__(256) void pack_kernel(float* __restrict__ wl,
                                                   float* __restrict__ wr) {
    const int g = blockIdx.x;                 // 0..1023
    const int right = (g >= NSITE) ? 1 : 0;
    const int s = right ? g - NSITE : g;
    float* base = (right ? wr : wl) + (size_t)s * (SLAB_BYTES / 4);

    __shared__ float2 st[DD * 65];            // padded [l][r] (w0,w1) pairs
    const float4* src4 = (const float4*)base; // 16B/lane loads
    for (int e4 = threadIdx.x; e4 < DD * DD / 2; e4 += 256) {
        const float4 v = src4[e4];
        const int e = e4 * 2;                 // e even -> same padded row for e, e+1
        float2* d = &st[(e >> 6) * 65 + (e & 63)];
        d[0] = make_float2(v.x, v.y);
        d[1] = make_float2(v.z, v.w);
    }
    __syncthreads();

    uint32_t* out = (uint32_t*)base;          // front 16 KB = 4096 dwords
    #pragma unroll
    for (int rr = 0; rr < 16; ++rr) {
        const int od = rr * 256 + threadIdx.x;        // coalesced writes
        const int chunk = od >> 8, i = chunk >> 3, sk = chunk & 7;
        const int H = (od >> 7) & 1, m5 = (od >> 2) & 31, d = od & 3;
        const int m = 32 * i + m5, k = 8 * sk + 4 * H + d;
        const float2 a = right ? st[m * 65 + k] : st[k * 65 + m];
        out[od] = pk2(a.x, a.y);              // lo = w0, hi = w1
    }
}

__device__ __forceinline__ void dma16(const void* gp, void* lp) {
    __builtin_amdgcn_global_load_lds(
        (const __attribute__((address_space(1))) uint32_t*)gp,
        (__attribute__((address_space(3))) uint32_t*)lp, 16, 0, 0);
}

// ---------------------------------------------------------------------------
// Stage 1.  Counter-driven (r8: VALU cut was neutral -> stall-bound,
// MfmaUtil 39% ~ in-cluster pipe idle): split the per-site K-sum into
// EVEN/ODD-sk accumulator sets.  Dependency depth 8 -> 4; independent MFMAs
// per level 4 -> 8, so issue covers result latency.  accE init = Identity,
// accO init = 0; extraction builds B-frags from (accE+accO) via v_pk_add;
// per-site chaining C=zf at sk=0 (accE) / sk=1 (accO).  DMA ring, vmcnt(8)
// cadence, barriers, setprio: UNCHANGED.
// ---------------------------------------------------------------------------
__global__ __launch_bounds__(256, 2) void stage1_kernel(
        const float* __restrict__ x, float* __restrict__ wl, float* __restrict__ wr) {
    const int bid  = blockIdx.x;          // 0..511
    const int side = bid >> 8;
    const int seg  = (bid >> 4) & 15;
    const int bq   = bid & 15;
    const int wave = threadIdx.x >> 6;
    const int lane = threadIdx.x & 63;
    const int b    = bq * 4 + wave;
    const int m5   = lane & 31;
    const int H    = lane >> 5;

    __shared__ __align__(16) char ring[4][PACK_BYTES];   // 64 KB
    __shared__ float2 xs[4][SEGLEN];

    char* wbuf = (char*)(side ? wr : wl);

    if (lane < SEGLEN) {
        const float2* xp = ((const float2*)x) + (size_t)b * 1024 + (side ? NSITE : 0);
        const int sg = seg * SEGLEN + (side ? SEGLEN - 1 - lane : lane);
        xs[wave][lane] = xp[sg];
    }

    auto siteAddr = [&](int t) -> const char* {
        const int sg = seg * SEGLEN + (side ? SEGLEN - 1 - t : t);
        return wbuf + (size_t)sg * SLAB_BYTES;
    };

    #pragma unroll
    for (int t0 = 0; t0 < 2; ++t0) {
        const char* sb = siteAddr(t0);
        #pragma unroll
        for (int c = 0; c < 4; ++c) {
            const int ch = wave * 4 + c;
            dma16(sb + ch * 1024 + lane * 16, ring[t0] + ch * 1024);
        }
    }

    // accE := Identity, accO := 0  (C/D layout: row=(q&3)+8(q>>2)+4H, col=32j+m5)
    f32x16 accE[2][2], accO[2][2];
    #pragma unroll
    for (int i = 0; i < 2; ++i)
        #pragma unroll
        for (int j = 0; j < 2; ++j)
            #pragma unroll
            for (int q = 0; q < 16; ++q) {
                const int row = (q & 3) + 8 * (q >> 2) + 4 * H;
                accE[i][j][q] = (i == j && row == m5) ? 1.f : 0.f;
                accO[i][j][q] = 0.f;
            }

    // persistent zero C-operand
    f32x16 zf;
    #pragma unroll
    for (int q = 0; q < 16; ++q) zf[q] = 0.f;

    union BU { bf16x8 v; uint32_t w[4]; };

    for (int t = 0; t < SEGLEN; ++t) {
        int t2 = t + 2; if (t2 > SEGLEN - 1) t2 = SEGLEN - 1;   // clamped dummy keeps cadence
        {
            const char* sb = siteAddr(t2);
            char* lb = ring[(t + 2) & 3];
            #pragma unroll
            for (int c = 0; c < 4; ++c) {
                const int ch = wave * 4 + c;
                dma16(sb + ch * 1024 + lane * 16, lb + ch * 1024);
            }
        }
        asm volatile("s_waitcnt vmcnt(8)" ::: "memory");
        asm volatile("s_barrier" ::: "memory");

        const char* rb = ring[t & 3];
        const float2 xv = xs[wave][t];
        const float2 xx = make_float2(xv.x, xv.x);
        const float2 xy = make_float2(xv.y, xv.y);

        // ---- pre-extract ALL B-fragments from (accE+accO); reads complete
        //      before any acc write below (SSA dataflow) ----
        BU bfa[8][2];                              // 64 dwords, static-indexed
        #pragma unroll
        for (int sk = 0; sk < 8; ++sk) {
            const int mi = sk >> 2, qb = 4 * (sk & 3);
            #pragma unroll
            for (int j = 0; j < 2; ++j)
                #pragma unroll
                for (int dp = 0; dp < 2; ++dp) {
                    const float2 e01 = make_float2(accE[mi][j][qb + 2 * dp],
                                                   accE[mi][j][qb + 2 * dp + 1]);
                    const float2 o01 = make_float2(accO[mi][j][qb + 2 * dp],
                                                   accO[mi][j][qb + 2 * dp + 1]);
                    const float2 v01 = pkadd2(e01, o01);
                    const float2 pa = pkmul2(xx, v01);   // {x0*v0, x0*v1}
                    const float2 pb = pkmul2(xy, v01);   // {x1*v0, x1*v1}
                    bfa[sk][j].w[2 * dp + 0] = pk2(pa.x, pb.x);  // kap even: x0
                    bfa[sk][j].w[2 * dp + 1] = pk2(pa.y, pb.y);  // kap odd : x1
                }
        }

        // ---- MFMA cluster: even sk -> accE, odd sk -> accO (depth 4 each,
        //      8 independent MFMAs per dependency level) ----
        __builtin_amdgcn_s_setprio(1);
        #pragma unroll
        for (int sk = 0; sk < 8; ++sk) {
            #pragma unroll
            for (int i = 0; i < 2; ++i) {
                union { bf16x8 v; uint4 u; } a;
                a.u = *(const uint4*)(rb + (i * 8 + sk) * 1024 + lane * 16);
                #pragma unroll
                for (int j = 0; j < 2; ++j) {
                    if (sk & 1)
                        accO[i][j] = __builtin_amdgcn_mfma_f32_32x32x16_bf16(
                            a.v, bfa[sk][j].v, (sk == 1) ? zf : accO[i][j], 0, 0, 0);
                    else
                        accE[i][j] = __builtin_amdgcn_mfma_f32_32x32x16_bf16(
                            a.v, bfa[sk][j].v, (sk == 0) ? zf : accE[i][j], 0, 0, 0);
                }
            }
        }
        __builtin_amdgcn_s_setprio(0);
    }

    // write P (final T = accE+accO, bf16, uint16 index c*64+r)
    {
        const int p = b * NSEG + seg;                    // 0..1023 per side
        char* pdst = wbuf + (size_t)(p >> 1) * SLAB_BYTES + PACK_BYTES + (p & 1) * 8192;
        #pragma unroll
        for (int i = 0; i < 2; ++i)
            #pragma unroll
            for (int j = 0; j < 2; ++j) {
                const int c = 32 * j + m5;
                #pragma unroll
                for (int Q = 0; Q < 4; ++Q) {
                    const int r0 = 32 * i + 8 * Q + 4 * H;
                    const float s0 = accE[i][j][4 * Q + 0] + accO[i][j][4 * Q + 0];
                    const float s1 = accE[i][j][4 * Q + 1] + accO[i][j][4 * Q + 1];
                    const float s2 = accE[i][j][4 * Q + 2] + accO[i][j][4 * Q + 2];
                    const float s3 = accE[i][j][4 * Q + 3] + accO[i][j][4 * Q + 3];
                    uint2 val;
                    val.x = pk2(s0, s1);
                    val.y = pk2(s2, s3);
                    *(uint2*)(pdst + c * 128 + r0 * 2) = val;
                }
            }
    }
    asm volatile("s_waitcnt vmcnt(0)" ::: "memory");   // drain DMA before endpgm
}

// ---------------------------------------------------------------------------
// Stage 2: fold 16 segment matrices into the boundary vector per chain.
// Register prefetch of next segment's P + raw s_barrier with lgkmcnt(0)
// only (no vmcnt drain) so prefetch loads stay in flight across barriers.
// ---------------------------------------------------------------------------
__global__ __launch_bounds__(256) void stage2_kernel(
        const float* __restrict__ wl, const float* __restrict__ wr,
        float* __restrict__ vbuf) {
    const int chain = blockIdx.x;        // 0..127
    const int side  = chain >> 6, b = chain & 63;
    const int tid   = threadIdx.x, r = tid & 63, cg = tid >> 6;
    const char* wbuf = (const char*)(side ? wr : wl);

    __shared__ float vsh[DD];
    __shared__ float part[4][DD];
    if (tid < DD) vsh[tid] = (tid == 0) ? 1.f : 0.f;

    auto Pseg = [&](int gi) -> const uint16_t* {
        const int g = side ? (NSEG - 1 - gi) : gi;
        const int p = b * NSEG + g;
        return (const uint16_t*)(wbuf
            + (size_t)(p >> 1) * SLAB_BYTES + PACK_BYTES + (p & 1) * 8192);
    };

    float pv[16];
    {
        const uint16_t* P = Pseg(0);
        #pragma unroll
        for (int cc = 0; cc < 16; ++cc)
            pv[cc] = __uint_as_float(((uint32_t)P[(cg * 16 + cc) * 64 + r]) << 16);
    }
    __syncthreads();

    for (int gi = 0; gi < NSEG; ++gi) {
        float nv[16];
        const bool more = (gi + 1 < NSEG);
        if (more) {
            const uint16_t* Pn = Pseg(gi + 1);          // issue early; waited at copy
            #pragma unroll
            for (int cc = 0; cc < 16; ++cc)
                nv[cc] = __uint_as_float(((uint32_t)Pn[(cg * 16 + cc) * 64 + r]) << 16);
        }
        float acc = 0.f;
        #pragma unroll
        for (int cc = 0; cc < 16; ++cc)
            acc = fmaf(vsh[cg * 16 + cc], pv[cc], acc);
        part[cg][r] = acc;
        asm volatile("s_waitcnt lgkmcnt(0)" ::: "memory");
        __builtin_amdgcn_s_barrier();
        if (tid < DD) vsh[tid] = part[0][tid] + part[1][tid] + part[2][tid] + part[3][tid];
        asm volatile("s_waitcnt lgkmcnt(0)" ::: "memory");
        __builtin_amdgcn_s_barrier();
        if (more) {
            #pragma unroll
            for (int cc = 0; cc < 16; ++cc) pv[cc] = nv[cc];
        }
    }
    if (tid < DD) vbuf[chain * DD + tid] = vsh[tid];
}

// out[b,o] = sum_{l,r} vL[b,l] * core[o,l,r] * wR[b,r]
__global__ __launch_bounds__(64) void finalize_kernel(
        const float* __restrict__ core,
        const float* __restrict__ vbuf,
        float* __restrict__ out) {
    const int b    = blockIdx.x;
    const int lane = threadIdx.x;
    __shared__ float vls[DD];
    vls[lane] = vbuf[b * DD + lane];
    const float wr = vbuf[(NB + b) * DD + lane];
    __syncthreads();
    for (int o = 0; o < NO; ++o) {
        float acc = 0.f;
        #pragma unroll 8
        for (int l = 0; l < DD; ++l)
            acc += vls[l] * core[(o * DD + l) * DD + lane];
        acc *= wr;
        #pragma unroll
        for (int off = 32; off > 0; off >>= 1)
            acc += __shfl_xor(acc, off, 64);
        if (lane == 0) out[b * NO + o] = acc;
    }
}

extern "C" void kernel_launch(void* const* d_in, const int* in_sizes, int n_in,
                              void* d_out, int out_size, void* d_ws, size_t ws_size,
                              hipStream_t stream) {
    const float* x    = (const float*)d_in[0];   // [64][1024][2]
    float*       wl   = (float*)d_in[1];         // [512][64][64][2] -> packed + P scratch
    const float* core = (const float*)d_in[2];   // [10][64][64]
    float*       wr   = (float*)d_in[3];         // [512][64][64][2] -> packed + P scratch
    float* vbuf = (float*)d_ws;                  // 32 KB

    pack_kernel<<<2 * NSITE, 256, 0, stream>>>(wl, wr);
    stage1_kernel<<<512, 256, 0, stream>>>(x, wl, wr);
    stage2_kernel<<<2 * NB, 256, 0, stream>>>(wl, wr, vbuf);
    finalize_kernel<<<NB, DD, 0, stream>>>(core, vbuf, (float*)d_out);
}

// Round 12
// 181.175 us; speedup vs baseline: 1.0141x; 1.0141x over previous
//
#include <hip/hip_runtime.h>
#include <stdint.h>

#define NSITE 512
#define DD    64
#define NB    64
#define NO    10
#define NSEG  16
#define SEGLEN 32
#define SLAB_BYTES 32768   // fp32 site slab stride
#define PACK_BYTES 16384   // packed bf16 Wstk image (front half of slab)

typedef short bf16x8 __attribute__((ext_vector_type(8)));
typedef float f32x16 __attribute__((ext_vector_type(16)));

// trunc-pack two f32 -> packed bf16 dword (lo=a, hi=b) in ONE v_perm_b32
__device__ __forceinline__ uint32_t pk2(float a, float b) {
    return __builtin_amdgcn_perm(__float_as_uint(b), __float_as_uint(a), 0x07060302);
}

// packed f32 pair multiply: one VOP3P instruction
__device__ __forceinline__ float2 pkmul2(float2 a, float2 b) {
    float2 r;
    asm("v_pk_mul_f32 %0, %1, %2" : "=v"(r) : "v"(a), "v"(b));
    return r;
}

// ---------------------------------------------------------------------------
// Pack W fp32 [s][l][r][w] -> bf16 K-stacked A-operand image, IN PLACE (front
// 16 KB of each 32 KB slab).  Layout as before; stage1 A-frag read is
// *(uint4*)(ring + chunk*1024 + lane*16): lane-contiguous, conflict-free.
// ---------------------------------------------------------------------------
__global__ __launch_bounds__(256) void pack_kernel(float* __restrict__ wl,
                                                   float* __restrict__ wr) {
    const int g = blockIdx.x;                 // 0..1023
    const int right = (g >= NSITE) ? 1 : 0;
    const int s = right ? g - NSITE : g;
    float* base = (right ? wr : wl) + (size_t)s * (SLAB_BYTES / 4);

    __shared__ float2 st[DD * 65];            // padded [l][r] (w0,w1) pairs
    const float4* src4 = (const float4*)base; // 16B/lane loads
    for (int e4 = threadIdx.x; e4 < DD * DD / 2; e4 += 256) {
        const float4 v = src4[e4];
        const int e = e4 * 2;                 // e even -> same padded row for e, e+1
        float2* d = &st[(e >> 6) * 65 + (e & 63)];
        d[0] = make_float2(v.x, v.y);
        d[1] = make_float2(v.z, v.w);
    }
    __syncthreads();

    uint32_t* out = (uint32_t*)base;          // front 16 KB = 4096 dwords
    #pragma unroll
    for (int rr = 0; rr < 16; ++rr) {
        const int od = rr * 256 + threadIdx.x;        // coalesced writes
        const int chunk = od >> 8, i = chunk >> 3, sk = chunk & 7;
        const int H = (od >> 7) & 1, m5 = (od >> 2) & 31, d = od & 3;
        const int m = 32 * i + m5, k = 8 * sk + 4 * H + d;
        const float2 a = right ? st[m * 65 + k] : st[k * 65 + m];
        out[od] = pk2(a.x, a.y);              // lo = w0, hi = w1
    }
}

__device__ __forceinline__ void dma16(const void* gp, void* lp) {
    __builtin_amdgcn_global_load_lds(
        (const __attribute__((address_space(1))) uint32_t*)gp,
        (__attribute__((address_space(3))) uint32_t*)lp, 16, 0, 0);
}

// ---------------------------------------------------------------------------
// Stage 1.  Counter history: r8 VALU cut (49->28%) neutral; r10 dep-split
// NEGATIVE (both in-cluster theories dead).  ~5500cyc/site-iter vs ~1300cyc
// of work => per-site vmcnt+barrier convoy dominates.  THIS ROUND: halve the
// sync points -- TWO sites per barrier.  Ring = 2 pair-slots of 32 KB.
// Cadence per iter: vmcnt(0) -> s_barrier -> issue pair u+1 -> compute sites
// 2u,2u+1.  Issue strictly AFTER the barrier so the destination slot (last
// read in iter u-1) is quiescent across all waves; chunk visibility = own
// vmcnt(0) then barrier.  Extraction / chained-acc MFMA identical to r8
// (absmax 0.0 measured).
// ---------------------------------------------------------------------------
__global__ __launch_bounds__(256, 2) void stage1_kernel(
        const float* __restrict__ x, float* __restrict__ wl, float* __restrict__ wr) {
    const int bid  = blockIdx.x;          // 0..511
    const int side = bid >> 8;
    const int seg  = (bid >> 4) & 15;
    const int bq   = bid & 15;
    const int wave = threadIdx.x >> 6;
    const int lane = threadIdx.x & 63;
    const int b    = bq * 4 + wave;
    const int m5   = lane & 31;
    const int H    = lane >> 5;

    __shared__ __align__(16) char ring[4][PACK_BYTES];   // 64 KB = 2 pair-slots
    __shared__ float2 xs[4][SEGLEN];

    char* wbuf = (char*)(side ? wr : wl);

    if (lane < SEGLEN) {
        const float2* xp = ((const float2*)x) + (size_t)b * 1024 + (side ? NSITE : 0);
        const int sg = seg * SEGLEN + (side ? SEGLEN - 1 - lane : lane);
        xs[wave][lane] = xp[sg];
    }

    auto siteAddr = [&](int t) -> const char* {
        const int sg = seg * SEGLEN + (side ? SEGLEN - 1 - t : t);
        return wbuf + (size_t)sg * SLAB_BYTES;
    };

    // prologue: pair 0 (sites 0,1) -> slot 0 (ring[0], ring[1])
    #pragma unroll
    for (int s01 = 0; s01 < 2; ++s01) {
        const char* sb = siteAddr(s01);
        #pragma unroll
        for (int c = 0; c < 4; ++c) {
            const int ch = wave * 4 + c;
            dma16(sb + ch * 1024 + lane * 16, ring[s01] + ch * 1024);
        }
    }

    // acc := Identity (C/D layout: row=(q&3)+8(q>>2)+4H, col=32j+m5)
    f32x16 acc[2][2];
    #pragma unroll
    for (int i = 0; i < 2; ++i)
        #pragma unroll
        for (int j = 0; j < 2; ++j)
            #pragma unroll
            for (int q = 0; q < 16; ++q) {
                const int row = (q & 3) + 8 * (q >> 2) + 4 * H;
                acc[i][j][q] = (i == j && row == m5) ? 1.f : 0.f;
            }

    // persistent zero C-operand
    f32x16 zf;
    #pragma unroll
    for (int q = 0; q < 16; ++q) zf[q] = 0.f;

    union BU { bf16x8 v; uint32_t w[4]; };

    for (int u = 0; u < 16; ++u) {
        asm volatile("s_waitcnt vmcnt(0)" ::: "memory");   // own pair-u chunks arrived
        asm volatile("s_barrier" ::: "memory");             // everyone's arrived; prev slot quiescent

        // issue pair u+1 (clamped dummy at u=15) -> slot (u+1)&1
        {
            int up = u + 1; if (up > 15) up = 15;
            #pragma unroll
            for (int s01 = 0; s01 < 2; ++s01) {
                const char* sb = siteAddr(2 * up + s01);
                char* lb = ring[2 * ((u + 1) & 1) + s01];
                #pragma unroll
                for (int c = 0; c < 4; ++c) {
                    const int ch = wave * 4 + c;
                    dma16(sb + ch * 1024 + lane * 16, lb + ch * 1024);
                }
            }
        }

        // compute the two sites of pair u (sequential: T-chain is serial)
        #pragma unroll
        for (int s01 = 0; s01 < 2; ++s01) {
            const char* rb = ring[2 * (u & 1) + s01];
            const float2 xv = xs[wave][2 * u + s01];
            const float2 xx = make_float2(xv.x, xv.x);
            const float2 xy = make_float2(xv.y, xv.y);

            // pre-extract ALL B-fragments from acc (reads precede writes; SSA)
            BU bfa[8][2];                              // 64 dwords, static-indexed
            #pragma unroll
            for (int sk = 0; sk < 8; ++sk) {
                const int mi = sk >> 2, qb = 4 * (sk & 3);
                #pragma unroll
                for (int j = 0; j < 2; ++j)
                    #pragma unroll
                    for (int dp = 0; dp < 2; ++dp) {
                        const float2 v01 = make_float2(acc[mi][j][qb + 2 * dp],
                                                       acc[mi][j][qb + 2 * dp + 1]);
                        const float2 pa = pkmul2(xx, v01);   // {x0*v0, x0*v1}
                        const float2 pb = pkmul2(xy, v01);   // {x1*v0, x1*v1}
                        bfa[sk][j].w[2 * dp + 0] = pk2(pa.x, pb.x);  // kap even: x0
                        bfa[sk][j].w[2 * dp + 1] = pk2(pa.y, pb.y);  // kap odd : x1
                    }
            }

            // MFMA cluster: chain directly into acc, C=zf at sk==0
            __builtin_amdgcn_s_setprio(1);
            #pragma unroll
            for (int sk = 0; sk < 8; ++sk) {
                #pragma unroll
                for (int i = 0; i < 2; ++i) {
                    union { bf16x8 v; uint4 u; } a;
                    a.u = *(const uint4*)(rb + (i * 8 + sk) * 1024 + lane * 16);
                    #pragma unroll
                    for (int j = 0; j < 2; ++j)
                        acc[i][j] = __builtin_amdgcn_mfma_f32_32x32x16_bf16(
                            a.v, bfa[sk][j].v, (sk == 0) ? zf : acc[i][j], 0, 0, 0);
                }
            }
            __builtin_amdgcn_s_setprio(0);
        }
    }

    // write P (final T, bf16, uint16 index c*64+r) into slab back-halves
    {
        const int p = b * NSEG + seg;                    // 0..1023 per side
        char* pdst = wbuf + (size_t)(p >> 1) * SLAB_BYTES + PACK_BYTES + (p & 1) * 8192;
        #pragma unroll
        for (int i = 0; i < 2; ++i)
            #pragma unroll
            for (int j = 0; j < 2; ++j) {
                const int c = 32 * j + m5;
                #pragma unroll
                for (int Q = 0; Q < 4; ++Q) {
                    const int r0 = 32 * i + 8 * Q + 4 * H;
                    uint2 val;
                    val.x = pk2(acc[i][j][4 * Q + 0], acc[i][j][4 * Q + 1]);
                    val.y = pk2(acc[i][j][4 * Q + 2], acc[i][j][4 * Q + 3]);
                    *(uint2*)(pdst + c * 128 + r0 * 2) = val;
                }
            }
    }
    asm volatile("s_waitcnt vmcnt(0)" ::: "memory");   // drain dummy DMA before endpgm
}

// ---------------------------------------------------------------------------
// Stage 2: fold 16 segment matrices into the boundary vector per chain.
// Register prefetch of next segment's P + raw s_barrier with lgkmcnt(0)
// only (no vmcnt drain) so prefetch loads stay in flight across barriers.
// ---------------------------------------------------------------------------
__global__ __launch_bounds__(256) void stage2_kernel(
        const float* __restrict__ wl, const float* __restrict__ wr,
        float* __restrict__ vbuf) {
    const int chain = blockIdx.x;        // 0..127
    const int side  = chain >> 6, b = chain & 63;
    const int tid   = threadIdx.x, r = tid & 63, cg = tid >> 6;
    const char* wbuf = (const char*)(side ? wr : wl);

    __shared__ float vsh[DD];
    __shared__ float part[4][DD];
    if (tid < DD) vsh[tid] = (tid == 0) ? 1.f : 0.f;

    auto Pseg = [&](int gi) -> const uint16_t* {
        const int g = side ? (NSEG - 1 - gi) : gi;
        const int p = b * NSEG + g;
        return (const uint16_t*)(wbuf
            + (size_t)(p >> 1) * SLAB_BYTES + PACK_BYTES + (p & 1) * 8192);
    };

    float pv[16];
    {
        const uint16_t* P = Pseg(0);
        #pragma unroll
        for (int cc = 0; cc < 16; ++cc)
            pv[cc] = __uint_as_float(((uint32_t)P[(cg * 16 + cc) * 64 + r]) << 16);
    }
    __syncthreads();

    for (int gi = 0; gi < NSEG; ++gi) {
        float nv[16];
        const bool more = (gi + 1 < NSEG);
        if (more) {
            const uint16_t* Pn = Pseg(gi + 1);          // issue early; waited at copy
            #pragma unroll
            for (int cc = 0; cc < 16; ++cc)
                nv[cc] = __uint_as_float(((uint32_t)Pn[(cg * 16 + cc) * 64 + r]) << 16);
        }
        float acc = 0.f;
        #pragma unroll
        for (int cc = 0; cc < 16; ++cc)
            acc = fmaf(vsh[cg * 16 + cc], pv[cc], acc);
        part[cg][r] = acc;
        asm volatile("s_waitcnt lgkmcnt(0)" ::: "memory");
        __builtin_amdgcn_s_barrier();
        if (tid < DD) vsh[tid] = part[0][tid] + part[1][tid] + part[2][tid] + part[3][tid];
        asm volatile("s_waitcnt lgkmcnt(0)" ::: "memory");
        __builtin_amdgcn_s_barrier();
        if (more) {
            #pragma unroll
            for (int cc = 0; cc < 16; ++cc) pv[cc] = nv[cc];
        }
    }
    if (tid < DD) vbuf[chain * DD + tid] = vsh[tid];
}

// out[b,o] = sum_{l,r} vL[b,l] * core[o,l,r] * wR[b,r]
__global__ __launch_bounds__(64) void finalize_kernel(
        const float* __restrict__ core,
        const float* __restrict__ vbuf,
        float* __restrict__ out) {
    const int b    = blockIdx.x;
    const int lane = threadIdx.x;
    __shared__ float vls[DD];
    vls[lane] = vbuf[b * DD + lane];
    const float wr = vbuf[(NB + b) * DD + lane];
    __syncthreads();
    for (int o = 0; o < NO; ++o) {
        float acc = 0.f;
        #pragma unroll 8
        for (int l = 0; l < DD; ++l)
            acc += vls[l] * core[(o * DD + l) * DD + lane];
        acc *= wr;
        #pragma unroll
        for (int off = 32; off > 0; off >>= 1)
            acc += __shfl_xor(acc, off, 64);
        if (lane == 0) out[b * NO + o] = acc;
    }
}

extern "C" void kernel_launch(void* const* d_in, const int* in_sizes, int n_in,
                              void* d_out, int out_size, void* d_ws, size_t ws_size,
                              hipStream_t stream) {
    const float* x    = (const float*)d_in[0];   // [64][1024][2]
    float*       wl   = (float*)d_in[1];         // [512][64][64][2] -> packed + P scratch
    const float* core = (const float*)d_in[2];   // [10][64][64]
    float*       wr   = (float*)d_in[3];         // [512][64][64][2] -> packed + P scratch
    float* vbuf = (float*)d_ws;                  // 32 KB

    pack_kernel<<<2 * NSITE, 256, 0, stream>>>(wl, wr);
    stage1_kernel<<<512, 256, 0, stream>>>(x, wl, wr);
    stage2_kernel<<<2 * NB, 256, 0, stream>>>(wl, wr, vbuf);
    finalize_kernel<<<NB, DD, 0, stream>>>(core, vbuf, (float*)d_out);
}

// Round 13
// 166.571 us; speedup vs baseline: 1.1030x; 1.0877x over previous
//
#include <hip/hip_runtime.h>
#include <stdint.h>

#define NSITE 512
#define DD    64
#define NB    64
#define NO    10
#define NSEG  16
#define SEGLEN 32
#define SLAB_BYTES 32768   // fp32 site slab stride
#define PACK_BYTES 16384   // packed bf16 Wstk image (front half of slab)

typedef short bf16x8 __attribute__((ext_vector_type(8)));
typedef float f32x16 __attribute__((ext_vector_type(16)));

// trunc-pack two f32 -> packed bf16 dword (lo=a, hi=b) in ONE v_perm_b32
__device__ __forceinline__ uint32_t pk2(float a, float b) {
    return __builtin_amdgcn_perm(__float_as_uint(b), __float_as_uint(a), 0x07060302);
}

// packed f32 pair multiply: one VOP3P instruction
__device__ __forceinline__ float2 pkmul2(float2 a, float2 b) {
    float2 r;
    asm("v_pk_mul_f32 %0, %1, %2" : "=v"(r) : "v"(a), "v"(b));
    return r;
}

// ---------------------------------------------------------------------------
// Pack W fp32 [s][l][r][w] -> bf16 K-stacked A-operand image, IN PLACE (front
// 16 KB of each 32 KB slab).  Unchanged (measured-good).
// ---------------------------------------------------------------------------
__global__ __launch_bounds__(256) void pack_kernel(float* __restrict__ wl,
                                                   float* __restrict__ wr) {
    const int g = blockIdx.x;                 // 0..1023
    const int right = (g >= NSITE) ? 1 : 0;
    const int s = right ? g - NSITE : g;
    float* base = (right ? wr : wl) + (size_t)s * (SLAB_BYTES / 4);

    __shared__ float2 st[DD * 65];            // padded [l][r] (w0,w1) pairs
    const float4* src4 = (const float4*)base; // 16B/lane loads
    for (int e4 = threadIdx.x; e4 < DD * DD / 2; e4 += 256) {
        const float4 v = src4[e4];
        const int e = e4 * 2;                 // e even -> same padded row for e, e+1
        float2* d = &st[(e >> 6) * 65 + (e & 63)];
        d[0] = make_float2(v.x, v.y);
        d[1] = make_float2(v.z, v.w);
    }
    __syncthreads();

    uint32_t* out = (uint32_t*)base;          // front 16 KB = 4096 dwords
    #pragma unroll
    for (int rr = 0; rr < 16; ++rr) {
        const int od = rr * 256 + threadIdx.x;        // coalesced writes
        const int chunk = od >> 8, i = chunk >> 3, sk = chunk & 7;
        const int H = (od >> 7) & 1, m5 = (od >> 2) & 31, d = od & 3;
        const int m = 32 * i + m5, k = 8 * sk + 4 * H + d;
        const float2 a = right ? st[m * 65 + k] : st[k * 65 + m];
        out[od] = pk2(a.x, a.y);              // lo = w0, hi = w1
    }
}

__device__ __forceinline__ void dma16(const void* gp, void* lp) {
    __builtin_amdgcn_global_load_lds(
        (const __attribute__((address_space(1))) uint32_t*)gp,
        (__attribute__((address_space(3))) uint32_t*)lp, 16, 0, 0);
}

// ---------------------------------------------------------------------------
// Stage 1.  REVERTED to the r8 cadence (best measured: 74.2us, 88 VGPR):
// 4-slot ring, per-site vmcnt(8)+s_barrier, bfa pre-extraction, chained acc.
// r10 (dep-split) and r12 (2-site/barrier) both regressed -> structure is at
// the documented 2-barrier ceiling (~36% MFMA).  NEW: XCD-aware bijective
// blockIdx swizzle (T1): lid=(pb&7)*64+(pb>>3) puts all 16 blocks of a
// (side,seg) slab-sharing group on ONE XCD -> L2-local W reads.  Readout:
// FETCH_SIZE 65.8MB (3.9x dup) -> ~20MB.
// ---------------------------------------------------------------------------
__global__ __launch_bounds__(256, 2) void stage1_kernel(
        const float* __restrict__ x, float* __restrict__ wl, float* __restrict__ wr) {
    const int pb   = blockIdx.x;          // physical 0..511
    const int bid  = (pb & 7) * 64 + (pb >> 3);   // logical, XCD-grouped
    const int side = bid >> 8;
    const int seg  = (bid >> 4) & 15;
    const int bq   = bid & 15;
    const int wave = threadIdx.x >> 6;
    const int lane = threadIdx.x & 63;
    const int b    = bq * 4 + wave;
    const int m5   = lane & 31;
    const int H    = lane >> 5;

    __shared__ __align__(16) char ring[4][PACK_BYTES];   // 64 KB
    __shared__ float2 xs[4][SEGLEN];

    char* wbuf = (char*)(side ? wr : wl);

    if (lane < SEGLEN) {
        const float2* xp = ((const float2*)x) + (size_t)b * 1024 + (side ? NSITE : 0);
        const int sg = seg * SEGLEN + (side ? SEGLEN - 1 - lane : lane);
        xs[wave][lane] = xp[sg];
    }

    auto siteAddr = [&](int t) -> const char* {
        const int sg = seg * SEGLEN + (side ? SEGLEN - 1 - t : t);
        return wbuf + (size_t)sg * SLAB_BYTES;
    };

    #pragma unroll
    for (int t0 = 0; t0 < 2; ++t0) {
        const char* sb = siteAddr(t0);
        #pragma unroll
        for (int c = 0; c < 4; ++c) {
            const int ch = wave * 4 + c;
            dma16(sb + ch * 1024 + lane * 16, ring[t0] + ch * 1024);
        }
    }

    // acc := Identity (C/D layout: row=(q&3)+8(q>>2)+4H, col=32j+m5)
    f32x16 acc[2][2];
    #pragma unroll
    for (int i = 0; i < 2; ++i)
        #pragma unroll
        for (int j = 0; j < 2; ++j)
            #pragma unroll
            for (int q = 0; q < 16; ++q) {
                const int row = (q & 3) + 8 * (q >> 2) + 4 * H;
                acc[i][j][q] = (i == j && row == m5) ? 1.f : 0.f;
            }

    // persistent zero C-operand
    f32x16 zf;
    #pragma unroll
    for (int q = 0; q < 16; ++q) zf[q] = 0.f;

    union BU { bf16x8 v; uint32_t w[4]; };

    for (int t = 0; t < SEGLEN; ++t) {
        int t2 = t + 2; if (t2 > SEGLEN - 1) t2 = SEGLEN - 1;   // clamped dummy keeps cadence
        {
            const char* sb = siteAddr(t2);
            char* lb = ring[(t + 2) & 3];
            #pragma unroll
            for (int c = 0; c < 4; ++c) {
                const int ch = wave * 4 + c;
                dma16(sb + ch * 1024 + lane * 16, lb + ch * 1024);
            }
        }
        asm volatile("s_waitcnt vmcnt(8)" ::: "memory");
        asm volatile("s_barrier" ::: "memory");

        const char* rb = ring[t & 3];
        const float2 xv = xs[wave][t];
        const float2 xx = make_float2(xv.x, xv.x);
        const float2 xy = make_float2(xv.y, xv.y);

        // pre-extract ALL B-fragments from acc (reads precede writes; SSA)
        BU bfa[8][2];                              // 64 dwords, static-indexed
        #pragma unroll
        for (int sk = 0; sk < 8; ++sk) {
            const int mi = sk >> 2, qb = 4 * (sk & 3);
            #pragma unroll
            for (int j = 0; j < 2; ++j)
                #pragma unroll
                for (int dp = 0; dp < 2; ++dp) {
                    const float2 v01 = make_float2(acc[mi][j][qb + 2 * dp],
                                                   acc[mi][j][qb + 2 * dp + 1]);
                    const float2 pa = pkmul2(xx, v01);   // {x0*v0, x0*v1}
                    const float2 pb = pkmul2(xy, v01);   // {x1*v0, x1*v1}
                    bfa[sk][j].w[2 * dp + 0] = pk2(pa.x, pb.x);  // kap even: x0
                    bfa[sk][j].w[2 * dp + 1] = pk2(pa.y, pb.y);  // kap odd : x1
                }
        }

        // MFMA cluster: chain directly into acc, C=zf at sk==0
        __builtin_amdgcn_s_setprio(1);
        #pragma unroll
        for (int sk = 0; sk < 8; ++sk) {
            #pragma unroll
            for (int i = 0; i < 2; ++i) {
                union { bf16x8 v; uint4 u; } a;
                a.u = *(const uint4*)(rb + (i * 8 + sk) * 1024 + lane * 16);
                #pragma unroll
                for (int j = 0; j < 2; ++j)
                    acc[i][j] = __builtin_amdgcn_mfma_f32_32x32x16_bf16(
                        a.v, bfa[sk][j].v, (sk == 0) ? zf : acc[i][j], 0, 0, 0);
            }
        }
        __builtin_amdgcn_s_setprio(0);
    }

    // write P (final T, bf16, uint16 index c*64+r) into slab back-halves
    {
        const int p = b * NSEG + seg;                    // 0..1023 per side
        char* pdst = wbuf + (size_t)(p >> 1) * SLAB_BYTES + PACK_BYTES + (p & 1) * 8192;
        #pragma unroll
        for (int i = 0; i < 2; ++i)
            #pragma unroll
            for (int j = 0; j < 2; ++j) {
                const int c = 32 * j + m5;
                #pragma unroll
                for (int Q = 0; Q < 4; ++Q) {
                    const int r0 = 32 * i + 8 * Q + 4 * H;
                    uint2 val;
                    val.x = pk2(acc[i][j][4 * Q + 0], acc[i][j][4 * Q + 1]);
                    val.y = pk2(acc[i][j][4 * Q + 2], acc[i][j][4 * Q + 3]);
                    *(uint2*)(pdst + c * 128 + r0 * 2) = val;
                }
            }
    }
    asm volatile("s_waitcnt vmcnt(0)" ::: "memory");   // drain DMA before endpgm
}

// ---------------------------------------------------------------------------
// FUSED stage2+finalize: 64 blocks (one per batch b) x 512 threads.
// Waves 0-3 fold the LEFT chain, waves 4-7 the RIGHT chain IN PARALLEL
// (critical path = 16 steps, same as the old 128-block stage2).  P-prefetch
// + lgkm-only raw barriers kept.  Then the o-contraction runs o-parallel
// across waves (o = wave, wave+8).  Saves one kernel launch and the vbuf
// global round-trip.
// ---------------------------------------------------------------------------
__global__ __launch_bounds__(512) void tail_kernel(
        const float* __restrict__ wl, const float* __restrict__ wr,
        const float* __restrict__ core, float* __restrict__ out) {
    const int b    = blockIdx.x;         // 0..63
    const int tid  = threadIdx.x;        // 0..511
    const int side = tid >> 8;           // waves 0-3: left, 4-7: right
    const int r    = tid & 63;
    const int cg   = (tid >> 6) & 3;
    const char* wbuf = (const char*)(side ? wr : wl);

    __shared__ float vsh[2][DD];
    __shared__ float part[2][4][DD];
    if ((tid & 255) < DD) vsh[side][r] = (r == 0) ? 1.f : 0.f;

    auto Pseg = [&](int gi) -> const uint16_t* {
        const int g = side ? (NSEG - 1 - gi) : gi;
        const int p = b * NSEG + g;
        return (const uint16_t*)(wbuf
            + (size_t)(p >> 1) * SLAB_BYTES + PACK_BYTES + (p & 1) * 8192);
    };

    float pv[16];
    {
        const uint16_t* P = Pseg(0);
        #pragma unroll
        for (int cc = 0; cc < 16; ++cc)
            pv[cc] = __uint_as_float(((uint32_t)P[(cg * 16 + cc) * 64 + r]) << 16);
    }
    __syncthreads();

    for (int gi = 0; gi < NSEG; ++gi) {
        float nv[16];
        const bool more = (gi + 1 < NSEG);
        if (more) {
            const uint16_t* Pn = Pseg(gi + 1);          // issue early; waited at copy
            #pragma unroll
            for (int cc = 0; cc < 16; ++cc)
                nv[cc] = __uint_as_float(((uint32_t)Pn[(cg * 16 + cc) * 64 + r]) << 16);
        }
        float acc = 0.f;
        #pragma unroll
        for (int cc = 0; cc < 16; ++cc)
            acc = fmaf(vsh[side][cg * 16 + cc], pv[cc], acc);
        part[side][cg][r] = acc;
        asm volatile("s_waitcnt lgkmcnt(0)" ::: "memory");
        __builtin_amdgcn_s_barrier();
        if ((tid & 255) < DD)
            vsh[side][r] = part[side][0][r] + part[side][1][r]
                         + part[side][2][r] + part[side][3][r];
        asm volatile("s_waitcnt lgkmcnt(0)" ::: "memory");
        __builtin_amdgcn_s_barrier();
        if (more) {
            #pragma unroll
            for (int cc = 0; cc < 16; ++cc) pv[cc] = nv[cc];
        }
    }
    // vsh[0] = vL, vsh[1] = wR.  o-parallel contraction across 8 waves.
    const int wv   = tid >> 6;           // 0..7
    const int lane = tid & 63;
    const float wrv = vsh[1][lane];
    for (int o = wv; o < NO; o += 8) {
        float acc = 0.f;
        #pragma unroll 8
        for (int l = 0; l < DD; ++l)
            acc += vsh[0][l] * core[(o * DD + l) * DD + lane];
        acc *= wrv;
        #pragma unroll
        for (int off = 32; off > 0; off >>= 1)
            acc += __shfl_xor(acc, off, 64);
        if (lane == 0) out[b * NO + o] = acc;
    }
}

extern "C" void kernel_launch(void* const* d_in, const int* in_sizes, int n_in,
                              void* d_out, int out_size, void* d_ws, size_t ws_size,
                              hipStream_t stream) {
    const float* x    = (const float*)d_in[0];   // [64][1024][2]
    float*       wl   = (float*)d_in[1];         // [512][64][64][2] -> packed + P scratch
    const float* core = (const float*)d_in[2];   // [10][64][64]
    float*       wr   = (float*)d_in[3];         // [512][64][64][2] -> packed + P scratch

    pack_kernel<<<2 * NSITE, 256, 0, stream>>>(wl, wr);
    stage1_kernel<<<512, 256, 0, stream>>>(x, wl, wr);
    tail_kernel<<<NB, 512, 0, stream>>>(wl, wr, core, (float*)d_out);
}